// Round 10
// baseline (105.002 us; speedup 1.0000x reference)
//
#include <hip/hip_runtime.h>
#include <hip/hip_bf16.h>

// PartiallyExchangeableNetwork on MI355X (gfx950)
// N=256, M=3, T=4096, ORDER=2 -> L=4094 windows, H=128, OUT=10
//
// h1 = relu(xin @ W1 + b1); h2 = relu(h1 @ W2 + b2); colsum over L.
// Layer 3 folded through the sum: sum_l(h2@W3+b3) = (sum_l h2)@W3 + L*b3 (tail).
//
// R10: all-32x32x16 LDS-free pipeline.
//  - W1 loaded with A-row channel permutation chan(m) = swap bits2<->3 of m,
//    so D1 regs 0-7 / 8-15 (after relu+cvt_pk, in element order) ARE the L2
//    B-fragments for K-chunks 2t / 2t+1. W2 fragments need no permutation.
//  - b1 via a k=9 ones-channel in xw; b2 via the L2 MFMA C operand.
//  - Each of 4 waves owns 32 outputs (w2f 32 VGPR) and walks all 32-row units.
//  - No h1 LDS, no unit barriers, ~140 VGPR -> 3 waves/SIMD, accs in VGPRs.

#define NN 256
#define MM 3
#define TT 4096
#define LL 4094
#define HH 128
#define CHUNKS 8           // 512 rows per block -> grid 2048
#define STAGES 2           // 2 stages of 256 rows
#define RPS 256
#define XROW 24            // xw row stride in halfwords (48B)

#define WS_W1 (1024 * 1024)            // after 1MB partials
#define WS_W2 (1024 * 1024 + 4096)     // w1t = 256 frags * 16B = 4KB

typedef __attribute__((ext_vector_type(8)))  short bf16x8;
typedef __attribute__((ext_vector_type(4)))  float f32x4;
typedef __attribute__((ext_vector_type(16))) float f32x16;
typedef __attribute__((ext_vector_type(4)))  unsigned int u32x4;
typedef __attribute__((ext_vector_type(2)))  unsigned int u32x2;

__device__ __forceinline__ unsigned short f2bf(float x) {
    __hip_bfloat16 h = __float2bfloat16(x);
    union { __hip_bfloat16 h; unsigned short u; } v; v.h = h;
    return v.u;
}
__device__ __forceinline__ unsigned pkbf2(float a, float b) {
    union { __hip_bfloat162 h; unsigned u; } v;
    v.h = __float22bfloat162_rn(make_float2(a, b));   // v_cvt_pk_bf16_f32
    return v.u;
}

// ---------------------------------------------------------------------------
// Prep: fragment tables.
// w1t[t][lane][e]: 32x32x16 A-frag for chan-tile t: A-row m = lane&31 holds
//   channel 32t + perm(m), perm = swap bits 2<->3; k = 8*(lane>>5)+e
//   (k<9: W1; k==9: b1 [pairs with xw's k=9 ones]; else 0).
// w2t[w][c][lane][e]: A-frag, o = 32w + (lane&31), k = 16c + 8*(lane>>5)+e.
// ---------------------------------------------------------------------------
__global__ void pen_prep(const float* __restrict__ w1, const float* __restrict__ b1,
                         const float* __restrict__ w2,
                         unsigned short* __restrict__ w1t,
                         unsigned short* __restrict__ w2t)
{
    const int tid = threadIdx.x;
    {   // 256 entries, one per thread
        const int t = tid >> 6, lane = tid & 63;
        const int m = lane & 31, h = lane >> 5;
        const int chan = 32 * t + ((m & 3) | ((m & 8) >> 1) | ((m & 4) << 1) | (m & 16));
        #pragma unroll
        for (int e = 0; e < 8; ++e) {
            const int k = 8 * h + e;
            float v = 0.f;
            if (k < 9)       v = w1[k * HH + chan];
            else if (k == 9) v = b1[chan];
            w1t[tid * 8 + e] = f2bf(v);
        }
    }
    for (int idx = tid; idx < 2048; idx += 256) {
        const int fid = idx >> 6, lane = idx & 63;
        const int w = fid >> 3, c = fid & 7;
        const int o = 32 * w + (lane & 31);
        #pragma unroll
        for (int e = 0; e < 8; ++e) {
            const int k = 16 * c + 8 * (lane >> 5) + e;
            w2t[idx * 8 + e] = f2bf(w2[k * HH + o]);
        }
    }
}

// ---------------------------------------------------------------------------
// Kernel A: block = (n, chunk of 512 rows); 2 stages of 256 rows; per stage
// 8 units of 32 rows, every wave does every unit for its 32 outputs.
// ---------------------------------------------------------------------------
__global__ __launch_bounds__(256, 3) void pen_inner(
    const float* __restrict__ x,
    const float* __restrict__ b2,
    const unsigned short* __restrict__ w1t,
    const unsigned short* __restrict__ w2t,
    float* __restrict__ partials)
{
    __shared__ __align__(16) unsigned short xw[XROW * RPS];   // 12.3 KB

    const int tid  = threadIdx.x;
    const int wave = tid >> 6;
    const int lane = tid & 63;
    const int lm   = lane & 31;    // 32x32 col (x-row) / A-row index
    const int lh   = lane >> 5;    // k-half

    const int bx    = blockIdx.x;
    const int n     = bx >> 3;
    const int chunk = bx & 7;

    const float* xn = x + n * (MM * TT);

    // ---- fragment tables -> registers ----
    bf16x8 w1f[4];
    #pragma unroll
    for (int t = 0; t < 4; ++t)
        w1f[t] = *(const bf16x8*)&w1t[(t * 64 + lane) * 8];
    bf16x8 w2f[8];
    #pragma unroll
    for (int c = 0; c < 8; ++c)
        w2f[c] = *(const bf16x8*)&w2t[((wave * 8 + c) * 64 + lane) * 8];
    f32x16 b2v;
    #pragma unroll
    for (int r = 0; r < 16; ++r)
        b2v[r] = b2[wave * 32 + (r & 3) + 8 * (r >> 2) + 4 * lh];

    const f32x16 zero16 = {0,0,0,0,0,0,0,0,0,0,0,0,0,0,0,0};
    const int xo = XROW * lm + 8 * lh;   // per-lane xw read offset (halfwords)
    f32x16 colsum = zero16;

    for (int st = 0; st < STAGES; ++st) {
        __syncthreads();   // prev stage's xw reads complete

        // ---- stage 256 window-rows as bf16; k=9 = 1.0 (bias ones-channel) ----
        {
            const int r = tid;                       // RPS == blockDim
            const int rowg = chunk * 512 + st * 256 + r;
            float kv[9];
            #pragma unroll
            for (int k = 0; k < 9; ++k) {            // k = i*3+m
                const int i = k / 3;
                const int m = k - i * 3;
                const int t = rowg + i;
                kv[k] = (t < TT) ? xn[m * TT + t] : 0.f;
            }
            u32x2 p0, p1, p2;
            p0[0] = pkbf2(kv[0], kv[1]); p0[1] = pkbf2(kv[2], kv[3]);
            p1[0] = pkbf2(kv[4], kv[5]); p1[1] = pkbf2(kv[6], kv[7]);
            p2[0] = pkbf2(kv[8], 1.0f);  p2[1] = 0u;     // k=9 ones-channel
            u32x2 z2; z2[0] = 0u; z2[1] = 0u;
            *(u32x2*)&xw[XROW * r]      = p0;
            *(u32x2*)&xw[XROW * r + 4]  = p1;
            *(u32x2*)&xw[XROW * r + 8]  = p2;
            *(u32x2*)&xw[XROW * r + 12] = z2;
            *(u32x2*)&xw[XROW * r + 16] = z2;
            *(u32x2*)&xw[XROW * r + 20] = z2;
        }
        __syncthreads();   // staging visible

        // ---- 8 units of 32 rows; no barriers, no h1 LDS ----
        #pragma unroll 2
        for (int u = 0; u < 8; ++u) {
            const bf16x8 bfrag = *(const bf16x8*)&xw[u * (XROW * 32) + xo];

            f32x16 acc2 = b2v;
            #pragma unroll
            for (int t = 0; t < 4; ++t) {
                f32x16 a1 = __builtin_amdgcn_mfma_f32_32x32x16_bf16(
                                w1f[t], bfrag, zero16, 0, 0, 0);
                u32x4 dA, dB;
                dA[0] = pkbf2(fmaxf(a1[0], 0.f),  fmaxf(a1[1], 0.f));
                dA[1] = pkbf2(fmaxf(a1[2], 0.f),  fmaxf(a1[3], 0.f));
                dA[2] = pkbf2(fmaxf(a1[4], 0.f),  fmaxf(a1[5], 0.f));
                dA[3] = pkbf2(fmaxf(a1[6], 0.f),  fmaxf(a1[7], 0.f));
                dB[0] = pkbf2(fmaxf(a1[8], 0.f),  fmaxf(a1[9], 0.f));
                dB[1] = pkbf2(fmaxf(a1[10], 0.f), fmaxf(a1[11], 0.f));
                dB[2] = pkbf2(fmaxf(a1[12], 0.f), fmaxf(a1[13], 0.f));
                dB[3] = pkbf2(fmaxf(a1[14], 0.f), fmaxf(a1[15], 0.f));
                const bf16x8 paA = __builtin_bit_cast(bf16x8, dA);
                const bf16x8 paB = __builtin_bit_cast(bf16x8, dB);
                acc2 = __builtin_amdgcn_mfma_f32_32x32x16_bf16(
                           w2f[2 * t],     paA, acc2, 0, 0, 0);
                acc2 = __builtin_amdgcn_mfma_f32_32x32x16_bf16(
                           w2f[2 * t + 1], paB, acc2, 0, 0, 0);
            }

            // relu + column-sum; tail rows 4094/4095 = (chunk7,st1,u7,lm>=30)
            const bool tailu = (chunk == CHUNKS - 1) && (st == STAGES - 1) && (u == 7);
            if (!(tailu && lm >= 30)) {
                #pragma unroll
                for (int r = 0; r < 16; ++r)
                    colsum[r] += fmaxf(acc2[r], 0.f);
            }
        }
    }

    // ---- reduce over the 32 col-lanes (within each half), write partials ----
    #pragma unroll
    for (int r = 0; r < 16; ++r) {
        float v = colsum[r];
        #pragma unroll
        for (int msk = 1; msk < 32; msk <<= 1)
            v += __shfl_xor(v, msk, 64);
        if (lm == 0) {
            const int o = wave * 32 + (r & 3) + 8 * (r >> 2) + 4 * lh;
            partials[(n * CHUNKS + chunk) * HH + o] = v;
        }
    }
}

// ---------------------------------------------------------------------------
// Kernel B: tail in fp32. inner = sum partials; oi = inner@W3 + L*b3;
// io = [x[:, :, :2] flat (6), oi]; g = relu(io@rw1+rb1); out = g@rw2+rb2.
// ---------------------------------------------------------------------------
__global__ __launch_bounds__(128) void pen_outer(
    const float* __restrict__ x,
    const float* __restrict__ w3, const float* __restrict__ b3,
    const float* __restrict__ rw1, const float* __restrict__ rb1,
    const float* __restrict__ rw2, const float* __restrict__ rb2,
    const float* __restrict__ partials,
    float* __restrict__ out)
{
    __shared__ float S[HH];
    __shared__ float IO[136];
    __shared__ float G[HH];
    const int n = blockIdx.x;
    const int c = threadIdx.x;

    float s = 0.f;
    #pragma unroll
    for (int ch = 0; ch < CHUNKS; ++ch)
        s += partials[(n * CHUNKS + ch) * HH + c];
    S[c] = s;
    if (c < 6) IO[c] = x[n * (MM * TT) + (c >> 1) * TT + (c & 1)];
    __syncthreads();

    float oi = (float)LL * b3[c];
    for (int k = 0; k < HH; ++k) oi += S[k] * w3[k * HH + c];
    IO[6 + c] = oi;
    __syncthreads();

    float g = rb1[c];
    for (int k = 0; k < 134; ++k) g += IO[k] * rw1[k * HH + c];
    G[c] = fmaxf(g, 0.f);
    __syncthreads();

    if (c < 10) {
        float o = rb2[c];
        for (int k = 0; k < HH; ++k) o += G[k] * rw2[k * 10 + c];
        out[n * 10 + c] = o;
    }
}

// ---------------------------------------------------------------------------
extern "C" void kernel_launch(void* const* d_in, const int* in_sizes, int n_in,
                              void* d_out, int out_size, void* d_ws, size_t ws_size,
                              hipStream_t stream)
{
    (void)in_sizes; (void)n_in; (void)out_size; (void)ws_size;
    const float* x   = (const float*)d_in[0];
    const float* w1  = (const float*)d_in[1];
    const float* b1  = (const float*)d_in[2];
    const float* w2  = (const float*)d_in[3];
    const float* b2  = (const float*)d_in[4];
    const float* w3  = (const float*)d_in[5];
    const float* b3  = (const float*)d_in[6];
    const float* rw1 = (const float*)d_in[7];
    const float* rb1 = (const float*)d_in[8];
    const float* rw2 = (const float*)d_in[9];
    const float* rb2 = (const float*)d_in[10];

    float*          partials = (float*)d_ws;                       // 1 MB
    unsigned short* w1t = (unsigned short*)((char*)d_ws + WS_W1);  // 4 KB
    unsigned short* w2t = (unsigned short*)((char*)d_ws + WS_W2);  // 32 KB

    pen_prep<<<1, 256, 0, stream>>>(w1, b1, w2, w1t, w2t);
    pen_inner<<<NN * CHUNKS, 256, 0, stream>>>(x, b2, w1t, w2t, partials);
    pen_outer<<<NN, 128, 0, stream>>>(x, w3, b3, rw1, rb1, rw2, rb2, partials,
                                      (float*)d_out);
}